// Round 1
// baseline (541.187 us; speedup 1.0000x reference)
//
#include <hip/hip_runtime.h>
#include <math.h>

#define BATCH 64
#define NV 1024
#define NL 512
#define DIM 512
#define TM 128
#define TN 64
#define KC 32
#define NRB (NV / TM)   // 8 row-blocks per batch

// One wave per row: sum of squares of DIM=512 floats.
__global__ __launch_bounds__(256) void norms_kernel(const float* __restrict__ x,
                                                    float* __restrict__ out, int rows) {
    int gw = (blockIdx.x * 256 + threadIdx.x) >> 6;   // global wave id
    int lane = threadIdx.x & 63;
    if (gw >= rows) return;
    const float4* p = (const float4*)(x + (size_t)gw * DIM);
    float4 v0 = p[lane];        // lanes 0..63 -> first 256 floats
    float4 v1 = p[lane + 64];   // next 256 floats
    float s = v0.x * v0.x + v0.y * v0.y + v0.z * v0.z + v0.w * v0.w +
              v1.x * v1.x + v1.y * v1.y + v1.z * v1.z + v1.w * v1.w;
#pragma unroll
    for (int off = 32; off > 0; off >>= 1) s += __shfl_down(s, off);
    if (lane == 0) out[gw] = s;
}

// Tiled inner-product + distance epilogue + row/col min.
// grid = (NRB, BATCH), block = 256. Each block: TM=128 video rows x all NL lang rows.
__global__ __launch_bounds__(256, 4) void distmin_kernel(
    const float* __restrict__ video, const float* __restrict__ lang,
    const float* __restrict__ nrm_v, const float* __restrict__ nrm_l,
    float* __restrict__ rowmin, float* __restrict__ colpart) {
    // A stored transposed: As[k][m]; +4 pad keeps 16B alignment for float4 reads.
    __shared__ float As[KC][TM + 4];
    __shared__ float Bs[KC][TN + 4];
    __shared__ float scred[TN][17];
    __shared__ float srow[TM][17];

    const int b = blockIdx.y;
    const int rb = blockIdx.x;
    const int rowBase = rb * TM;
    const float* Ag = video + (size_t)b * NV * DIM + (size_t)rowBase * DIM;
    const float* Bg = lang + (size_t)b * NL * DIM;
    const int tid = threadIdx.x;
    const int tc = tid & 15;   // column group: cols tc*4 .. tc*4+3
    const int tr = tid >> 4;   // row group:    rows tr*8 .. tr*8+7

    float anorm[8];
#pragma unroll
    for (int i = 0; i < 8; i++) anorm[i] = nrm_v[b * NV + rowBase + tr * 8 + i];

    float rmin[8];
#pragma unroll
    for (int i = 0; i < 8; i++) rmin[i] = INFINITY;

    for (int ct = 0; ct < NL / TN; ++ct) {
        float acc[8][4];
#pragma unroll
        for (int i = 0; i < 8; i++)
#pragma unroll
            for (int j = 0; j < 4; j++) acc[i][j] = 0.0f;

        for (int k0 = 0; k0 < DIM; k0 += KC) {
            __syncthreads();  // previous tile's LDS reads complete
            // Stage A chunk: 128 rows x 32 k (transposed into As[k][m]).
            // 1024 float4s, 4 per thread; 8 threads cover one row's 32 k's (coalesced 128B/row).
#pragma unroll
            for (int t = 0; t < 4; ++t) {
                int u = tid + t * 256;
                int row = u >> 3;
                int kq = (u & 7) * 4;
                float4 v = *(const float4*)(Ag + (size_t)row * DIM + k0 + kq);
                As[kq + 0][row] = v.x;
                As[kq + 1][row] = v.y;
                As[kq + 2][row] = v.z;
                As[kq + 3][row] = v.w;
            }
            // Stage B chunk: 64 lang rows x 32 k.
#pragma unroll
            for (int t = 0; t < 2; ++t) {
                int u = tid + t * 256;
                int row = u >> 3;
                int kq = (u & 7) * 4;
                float4 v = *(const float4*)(Bg + (size_t)(ct * TN + row) * DIM + k0 + kq);
                Bs[kq + 0][row] = v.x;
                Bs[kq + 1][row] = v.y;
                Bs[kq + 2][row] = v.z;
                Bs[kq + 3][row] = v.w;
            }
            __syncthreads();
#pragma unroll
            for (int k = 0; k < KC; ++k) {
                float4 a0 = *(const float4*)&As[k][tr * 8];
                float4 a1 = *(const float4*)&As[k][tr * 8 + 4];
                float4 bv = *(const float4*)&Bs[k][tc * 4];
                float a[8] = {a0.x, a0.y, a0.z, a0.w, a1.x, a1.y, a1.z, a1.w};
                float bb[4] = {bv.x, bv.y, bv.z, bv.w};
#pragma unroll
                for (int i = 0; i < 8; i++)
#pragma unroll
                    for (int j = 0; j < 4; j++) acc[i][j] = fmaf(a[i], bb[j], acc[i][j]);
            }
        }

        // Epilogue for this column tile: dist = |x|^2 - 2ab + |y|^2, update mins.
        float bnorm[4];
#pragma unroll
        for (int j = 0; j < 4; j++) bnorm[j] = nrm_l[b * NL + ct * TN + tc * 4 + j];
        float cmin[4] = {INFINITY, INFINITY, INFINITY, INFINITY};
#pragma unroll
        for (int i = 0; i < 8; i++) {
#pragma unroll
            for (int j = 0; j < 4; j++) {
                float d = anorm[i] - 2.0f * acc[i][j] + bnorm[j];
                rmin[i] = fminf(rmin[i], d);
                cmin[j] = fminf(cmin[j], d);
            }
        }
        __syncthreads();
#pragma unroll
        for (int j = 0; j < 4; j++) scred[tc * 4 + j][tr] = cmin[j];
        __syncthreads();
        if (tid < TN) {
            float m = INFINITY;
#pragma unroll
            for (int t = 0; t < 16; t++) m = fminf(m, scred[tid][t]);
            colpart[((size_t)(b * NRB + rb)) * NL + ct * TN + tid] = m;
        }
    }

    // Row-min reduce across the 16 column-group threads per row.
#pragma unroll
    for (int i = 0; i < 8; i++) srow[tr * 8 + i][tc] = rmin[i];
    __syncthreads();
    if (tid < TM) {
        float m = INFINITY;
#pragma unroll
        for (int t = 0; t < 16; t++) m = fminf(m, srow[tid][t]);
        rowmin[b * NV + rowBase + tid] = m;
    }
}

// One block per batch: out[b] = sum(rowmin)/NV + sum(min over rb of colpart)/NL
__global__ __launch_bounds__(256) void reduce_kernel(const float* __restrict__ rowmin,
                                                     const float* __restrict__ colpart,
                                                     float* __restrict__ out) {
    int b = blockIdx.x;
    int tid = threadIdx.x;
    float s = 0.0f;
    for (int v = tid; v < NV; v += 256) s += rowmin[b * NV + v] * (1.0f / NV);
    for (int l = tid; l < NL; l += 256) {
        float m = INFINITY;
#pragma unroll
        for (int rb = 0; rb < NRB; rb++) m = fminf(m, colpart[((size_t)(b * NRB + rb)) * NL + l]);
        s += m * (1.0f / NL);
    }
    __shared__ float red[4];
#pragma unroll
    for (int off = 32; off > 0; off >>= 1) s += __shfl_down(s, off);
    if ((tid & 63) == 0) red[tid >> 6] = s;
    __syncthreads();
    if (tid == 0) out[b] = red[0] + red[1] + red[2] + red[3];
}

extern "C" void kernel_launch(void* const* d_in, const int* in_sizes, int n_in,
                              void* d_out, int out_size, void* d_ws, size_t ws_size,
                              hipStream_t stream) {
    const float* video = (const float*)d_in[0];  // [64,1024,512]
    const float* lang = (const float*)d_in[1];   // [64,512,512]
    float* out = (float*)d_out;                  // [64]

    float* nrm_v = (float*)d_ws;                 // B*NV floats
    float* nrm_l = nrm_v + BATCH * NV;           // B*NL floats
    float* rowmin = nrm_l + BATCH * NL;          // B*NV floats
    float* colpart = rowmin + BATCH * NV;        // B*NRB*NL floats

    norms_kernel<<<(BATCH * NV) / 4, 256, 0, stream>>>(video, nrm_v, BATCH * NV);
    norms_kernel<<<(BATCH * NL) / 4, 256, 0, stream>>>(lang, nrm_l, BATCH * NL);

    dim3 grid(NRB, BATCH);
    distmin_kernel<<<grid, 256, 0, stream>>>(video, lang, nrm_v, nrm_l, rowmin, colpart);

    reduce_kernel<<<BATCH, 256, 0, stream>>>(rowmin, colpart, out);
}

// Round 2
// 113.657 us; speedup vs baseline: 4.7616x; 4.7616x over previous
//
#include <hip/hip_runtime.h>
#include <math.h>

#define BATCH 64
#define NV 1024
#define NL 512
#define DIM 512

typedef __bf16 bf16x8 __attribute__((ext_vector_type(8)));
typedef float f32x4 __attribute__((ext_vector_type(4)));

__device__ __forceinline__ ushort f2bf(float f) {
    union { float f; unsigned u; } c;
    c.f = f;
    unsigned u = c.u;
    return (ushort)((u + 0x7fffu + ((u >> 16) & 1u)) >> 16);  // RNE
}

__device__ __forceinline__ void gload16(const void* g, void* lds) {
    __builtin_amdgcn_global_load_lds((const __attribute__((address_space(1))) void*)g,
                                     (__attribute__((address_space(3))) void*)lds,
                                     16, 0, 0);
}

// ---------------- fused convert (fp32 -> bf16) + row sum-of-squares ----------
// One wave per row of DIM=512 floats.
__global__ __launch_bounds__(256) void convert_norms_kernel(
    const float* __restrict__ x, ushort* __restrict__ xb,
    float* __restrict__ nrm, int rows) {
    int gw = (blockIdx.x * 256 + threadIdx.x) >> 6;
    int lane = threadIdx.x & 63;
    if (gw >= rows) return;
    const float4* p = (const float4*)(x + (size_t)gw * DIM);
    float4 v0 = p[lane];
    float4 v1 = p[lane + 64];
    float s = v0.x * v0.x + v0.y * v0.y + v0.z * v0.z + v0.w * v0.w +
              v1.x * v1.x + v1.y * v1.y + v1.z * v1.z + v1.w * v1.w;
    ushort4 o0, o1;
    o0.x = f2bf(v0.x); o0.y = f2bf(v0.y); o0.z = f2bf(v0.z); o0.w = f2bf(v0.w);
    o1.x = f2bf(v1.x); o1.y = f2bf(v1.y); o1.z = f2bf(v1.z); o1.w = f2bf(v1.w);
    ushort* ob = xb + (size_t)gw * DIM;
    *(ushort4*)(ob + lane * 4) = o0;
    *(ushort4*)(ob + 256 + lane * 4) = o1;
#pragma unroll
    for (int off = 32; off > 0; off >>= 1) s += __shfl_down(s, off);
    if (lane == 0) nrm[gw] = s;
}

// ---------------- MFMA distance + min kernel --------------------------------
// grid = (32, 64): x -> (mt = x>>2 of 8, nt = x&3 of 4), y -> batch.
// block = 256 (4 waves, 2x2 over a 128x128 output tile; each wave 64x64).
#define TMM 128
#define TNN 128
#define BK 32
__global__ __launch_bounds__(256, 2) void distmin_mfma_kernel(
    const ushort* __restrict__ vbf, const ushort* __restrict__ lbf,
    const float* __restrict__ nrm_v, const float* __restrict__ nrm_l,
    float* __restrict__ rowpart, float* __restrict__ colpart) {
    __shared__ ushort AsU[TMM * BK];   // 8 KB, [row][k] linear
    __shared__ ushort BsU[TNN * BK];   // 8 KB, [col][k] linear
    __shared__ float rowred[2][TMM];
    __shared__ float colred[2][TNN];

    const int b = blockIdx.y;
    const int mt = blockIdx.x >> 2;
    const int nt = blockIdx.x & 3;
    const int tid = threadIdx.x;
    const int w = tid >> 6;
    const int lane = tid & 63;
    const int wrow = w >> 1;   // 0..1
    const int wcol = w & 1;    // 0..1

    const ushort* Abase = vbf + ((size_t)b * NV + (size_t)mt * TMM) * DIM;
    const ushort* Bbase = lbf + ((size_t)b * NL + (size_t)nt * TNN) * DIM;

    // staging geometry: chunk c = w*2+t covers rows [c*16, c*16+16), 1KB each.
    const int srow0 = lane >> 2;          // 0..15 within chunk
    const int skb = (lane & 3) * 16;      // byte offset within 64B row

    f32x4 acc[4][4];
#pragma unroll
    for (int i = 0; i < 4; i++)
#pragma unroll
        for (int j = 0; j < 4; j++) acc[i][j] = (f32x4){0.f, 0.f, 0.f, 0.f};

    const int lr = lane & 15;
    const int lk = (lane >> 4) * 8;

    for (int k0 = 0; k0 < DIM; k0 += BK) {
        __syncthreads();  // prior iteration's LDS reads done
#pragma unroll
        for (int t = 0; t < 2; ++t) {
            int c = w * 2 + t;
            int row = c * 16 + srow0;
            gload16((const char*)(Abase + (size_t)row * DIM + k0) + skb,
                    (char*)AsU + c * 1024);
            gload16((const char*)(Bbase + (size_t)row * DIM + k0) + skb,
                    (char*)BsU + c * 1024);
        }
        __syncthreads();  // vmcnt(0) drain emitted here by compiler

        bf16x8 av[4], bv[4];
#pragma unroll
        for (int fr = 0; fr < 4; ++fr)
            av[fr] = *(const bf16x8*)&AsU[(wrow * 64 + fr * 16 + lr) * BK + lk];
#pragma unroll
        for (int fc = 0; fc < 4; ++fc)
            bv[fc] = *(const bf16x8*)&BsU[(wcol * 64 + fc * 16 + lr) * BK + lk];
#pragma unroll
        for (int fr = 0; fr < 4; ++fr)
#pragma unroll
            for (int fc = 0; fc < 4; ++fc)
                acc[fr][fc] = __builtin_amdgcn_mfma_f32_16x16x32_bf16(
                    av[fr], bv[fc], acc[fr][fc], 0, 0, 0);
    }

    // ---- epilogue: d = |v|^2 - 2 dot + |l|^2, row/col mins ----
    const int rgrp = (lane >> 4) * 4;
    float anorm[4][4];
#pragma unroll
    for (int fr = 0; fr < 4; ++fr)
#pragma unroll
        for (int r = 0; r < 4; ++r)
            anorm[fr][r] = nrm_v[b * NV + mt * TMM + wrow * 64 + fr * 16 + rgrp + r];
    float bnorm[4];
#pragma unroll
    for (int fc = 0; fc < 4; ++fc)
        bnorm[fc] = nrm_l[b * NL + nt * TNN + wcol * 64 + fc * 16 + lr];

    float rmin[4][4];
    float cmin[4];
#pragma unroll
    for (int fr = 0; fr < 4; ++fr)
#pragma unroll
        for (int r = 0; r < 4; ++r) rmin[fr][r] = INFINITY;
#pragma unroll
    for (int fc = 0; fc < 4; ++fc) cmin[fc] = INFINITY;

#pragma unroll
    for (int fr = 0; fr < 4; ++fr)
#pragma unroll
        for (int fc = 0; fc < 4; ++fc)
#pragma unroll
            for (int r = 0; r < 4; ++r) {
                float d = anorm[fr][r] - 2.0f * acc[fr][fc][r] + bnorm[fc];
                rmin[fr][r] = fminf(rmin[fr][r], d);
                cmin[fc] = fminf(cmin[fc], d);
            }

    // row-min: reduce across the 16 lanes holding the 16 cols of a fragment
#pragma unroll
    for (int fr = 0; fr < 4; ++fr)
#pragma unroll
        for (int r = 0; r < 4; ++r) {
#pragma unroll
            for (int off = 1; off < 16; off <<= 1)
                rmin[fr][r] = fminf(rmin[fr][r], __shfl_xor(rmin[fr][r], off));
        }
    // col-min: reduce across the 4 row-groups (lane>>4)
#pragma unroll
    for (int fc = 0; fc < 4; ++fc) {
#pragma unroll
        for (int off = 16; off < 64; off <<= 1)
            cmin[fc] = fminf(cmin[fc], __shfl_xor(cmin[fc], off));
    }

    if ((lane & 15) == 0) {
#pragma unroll
        for (int fr = 0; fr < 4; ++fr)
#pragma unroll
            for (int r = 0; r < 4; ++r)
                rowred[wcol][wrow * 64 + fr * 16 + rgrp + r] = rmin[fr][r];
    }
    if (lane < 16) {
#pragma unroll
        for (int fc = 0; fc < 4; ++fc)
            colred[wrow][wcol * 64 + fc * 16 + lane] = cmin[fc];
    }
    __syncthreads();
    if (tid < TMM) {
        rowpart[((size_t)(b * 4 + nt)) * NV + mt * TMM + tid] =
            fminf(rowred[0][tid], rowred[1][tid]);
    } else {
        int c2 = tid - TMM;
        colpart[((size_t)(b * 8 + mt)) * NL + nt * TNN + c2] =
            fminf(colred[0][c2], colred[1][c2]);
    }
}

// ---------------- final reduce ----------------------------------------------
__global__ __launch_bounds__(256) void reduce2_kernel(
    const float* __restrict__ rowpart, const float* __restrict__ colpart,
    float* __restrict__ out) {
    int b = blockIdx.x;
    int tid = threadIdx.x;
    float s = 0.0f;
    for (int r = tid; r < NV; r += 256) {
        float m = INFINITY;
#pragma unroll
        for (int nt = 0; nt < 4; nt++)
            m = fminf(m, rowpart[((size_t)(b * 4 + nt)) * NV + r]);
        s += m * (1.0f / NV);
    }
    for (int c = tid; c < NL; c += 256) {
        float m = INFINITY;
#pragma unroll
        for (int mt = 0; mt < 8; mt++)
            m = fminf(m, colpart[((size_t)(b * 8 + mt)) * NL + c]);
        s += m * (1.0f / NL);
    }
    __shared__ float red[4];
#pragma unroll
    for (int off = 32; off > 0; off >>= 1) s += __shfl_down(s, off);
    if ((tid & 63) == 0) red[tid >> 6] = s;
    __syncthreads();
    if (tid == 0) out[b] = red[0] + red[1] + red[2] + red[3];
}

// =================== fallback fp32 path (round-1, known-good) ================
#define TM 128
#define TN 64
#define KC 32
#define NRB (NV / TM)

__global__ __launch_bounds__(256) void norms_kernel(const float* __restrict__ x,
                                                    float* __restrict__ out, int rows) {
    int gw = (blockIdx.x * 256 + threadIdx.x) >> 6;
    int lane = threadIdx.x & 63;
    if (gw >= rows) return;
    const float4* p = (const float4*)(x + (size_t)gw * DIM);
    float4 v0 = p[lane];
    float4 v1 = p[lane + 64];
    float s = v0.x * v0.x + v0.y * v0.y + v0.z * v0.z + v0.w * v0.w +
              v1.x * v1.x + v1.y * v1.y + v1.z * v1.z + v1.w * v1.w;
#pragma unroll
    for (int off = 32; off > 0; off >>= 1) s += __shfl_down(s, off);
    if (lane == 0) out[gw] = s;
}

__global__ __launch_bounds__(256, 4) void distmin_kernel(
    const float* __restrict__ video, const float* __restrict__ lang,
    const float* __restrict__ nrm_v, const float* __restrict__ nrm_l,
    float* __restrict__ rowmin, float* __restrict__ colpart) {
    __shared__ float As[KC][TM + 4];
    __shared__ float Bs[KC][TN + 4];
    __shared__ float scred[TN][17];
    __shared__ float srow[TM][17];

    const int b = blockIdx.y;
    const int rb = blockIdx.x;
    const int rowBase = rb * TM;
    const float* Ag = video + (size_t)b * NV * DIM + (size_t)rowBase * DIM;
    const float* Bg = lang + (size_t)b * NL * DIM;
    const int tid = threadIdx.x;
    const int tc = tid & 15;
    const int tr = tid >> 4;

    float anorm[8];
#pragma unroll
    for (int i = 0; i < 8; i++) anorm[i] = nrm_v[b * NV + rowBase + tr * 8 + i];
    float rmin[8];
#pragma unroll
    for (int i = 0; i < 8; i++) rmin[i] = INFINITY;

    for (int ct = 0; ct < NL / TN; ++ct) {
        float acc[8][4];
#pragma unroll
        for (int i = 0; i < 8; i++)
#pragma unroll
            for (int j = 0; j < 4; j++) acc[i][j] = 0.0f;

        for (int k0 = 0; k0 < DIM; k0 += KC) {
            __syncthreads();
#pragma unroll
            for (int t = 0; t < 4; ++t) {
                int u = tid + t * 256;
                int row = u >> 3;
                int kq = (u & 7) * 4;
                float4 v = *(const float4*)(Ag + (size_t)row * DIM + k0 + kq);
                As[kq + 0][row] = v.x;
                As[kq + 1][row] = v.y;
                As[kq + 2][row] = v.z;
                As[kq + 3][row] = v.w;
            }
#pragma unroll
            for (int t = 0; t < 2; ++t) {
                int u = tid + t * 256;
                int row = u >> 3;
                int kq = (u & 7) * 4;
                float4 v = *(const float4*)(Bg + (size_t)(ct * TN + row) * DIM + k0 + kq);
                Bs[kq + 0][row] = v.x;
                Bs[kq + 1][row] = v.y;
                Bs[kq + 2][row] = v.z;
                Bs[kq + 3][row] = v.w;
            }
            __syncthreads();
#pragma unroll
            for (int k = 0; k < KC; ++k) {
                float4 a0 = *(const float4*)&As[k][tr * 8];
                float4 a1 = *(const float4*)&As[k][tr * 8 + 4];
                float4 bvv = *(const float4*)&Bs[k][tc * 4];
                float a[8] = {a0.x, a0.y, a0.z, a0.w, a1.x, a1.y, a1.z, a1.w};
                float bb[4] = {bvv.x, bvv.y, bvv.z, bvv.w};
#pragma unroll
                for (int i = 0; i < 8; i++)
#pragma unroll
                    for (int j = 0; j < 4; j++) acc[i][j] = fmaf(a[i], bb[j], acc[i][j]);
            }
        }

        float bnorm[4];
#pragma unroll
        for (int j = 0; j < 4; j++) bnorm[j] = nrm_l[b * NL + ct * TN + tc * 4 + j];
        float cmin[4] = {INFINITY, INFINITY, INFINITY, INFINITY};
#pragma unroll
        for (int i = 0; i < 8; i++) {
#pragma unroll
            for (int j = 0; j < 4; j++) {
                float d = anorm[i] - 2.0f * acc[i][j] + bnorm[j];
                rmin[i] = fminf(rmin[i], d);
                cmin[j] = fminf(cmin[j], d);
            }
        }
        __syncthreads();
#pragma unroll
        for (int j = 0; j < 4; j++) scred[tc * 4 + j][tr] = cmin[j];
        __syncthreads();
        if (tid < TN) {
            float m = INFINITY;
#pragma unroll
            for (int t = 0; t < 16; t++) m = fminf(m, scred[tid][t]);
            colpart[((size_t)(b * NRB + rb)) * NL + ct * TN + tid] = m;
        }
    }

#pragma unroll
    for (int i = 0; i < 8; i++) srow[tr * 8 + i][tc] = rmin[i];
    __syncthreads();
    if (tid < TM) {
        float m = INFINITY;
#pragma unroll
        for (int t = 0; t < 16; t++) m = fminf(m, srow[tid][t]);
        rowmin[b * NV + rowBase + tid] = m;
    }
}

__global__ __launch_bounds__(256) void reduce_kernel(const float* __restrict__ rowmin,
                                                     const float* __restrict__ colpart,
                                                     float* __restrict__ out) {
    int b = blockIdx.x;
    int tid = threadIdx.x;
    float s = 0.0f;
    for (int v = tid; v < NV; v += 256) s += rowmin[b * NV + v] * (1.0f / NV);
    for (int l = tid; l < NL; l += 256) {
        float m = INFINITY;
#pragma unroll
        for (int rb = 0; rb < NRB; rb++) m = fminf(m, colpart[((size_t)(b * NRB + rb)) * NL + l]);
        s += m * (1.0f / NL);
    }
    __shared__ float red[4];
#pragma unroll
    for (int off = 32; off > 0; off >>= 1) s += __shfl_down(s, off);
    if ((tid & 63) == 0) red[tid >> 6] = s;
    __syncthreads();
    if (tid == 0) out[b] = red[0] + red[1] + red[2] + red[3];
}

// ============================================================================
extern "C" void kernel_launch(void* const* d_in, const int* in_sizes, int n_in,
                              void* d_out, int out_size, void* d_ws, size_t ws_size,
                              hipStream_t stream) {
    const float* video = (const float*)d_in[0];
    const float* lang = (const float*)d_in[1];
    float* out = (float*)d_out;

    // fast-path workspace layout (bytes)
    size_t off = 0;
    float* nrm_v = (float*)((char*)d_ws + off); off += (size_t)BATCH * NV * 4;
    float* nrm_l = (float*)((char*)d_ws + off); off += (size_t)BATCH * NL * 4;
    float* rowpart = (float*)((char*)d_ws + off); off += (size_t)BATCH * 4 * NV * 4;
    float* colpart = (float*)((char*)d_ws + off); off += (size_t)BATCH * 8 * NL * 4;
    ushort* vbf = (ushort*)((char*)d_ws + off); off += (size_t)BATCH * NV * DIM * 2;
    ushort* lbf = (ushort*)((char*)d_ws + off); off += (size_t)BATCH * NL * DIM * 2;

    if (ws_size >= off) {
        convert_norms_kernel<<<(BATCH * NV) / 4, 256, 0, stream>>>(video, vbf, nrm_v, BATCH * NV);
        convert_norms_kernel<<<(BATCH * NL) / 4, 256, 0, stream>>>(lang, lbf, nrm_l, BATCH * NL);
        dim3 grid(32, BATCH);
        distmin_mfma_kernel<<<grid, 256, 0, stream>>>(vbf, lbf, nrm_v, nrm_l, rowpart, colpart);
        reduce2_kernel<<<BATCH, 256, 0, stream>>>(rowpart, colpart, out);
    } else {
        // fallback fp32 path
        float* f_nrm_v = (float*)d_ws;
        float* f_nrm_l = f_nrm_v + BATCH * NV;
        float* f_rowmin = f_nrm_l + BATCH * NL;
        float* f_colpart = f_rowmin + BATCH * NV;
        norms_kernel<<<(BATCH * NV) / 4, 256, 0, stream>>>(video, f_nrm_v, BATCH * NV);
        norms_kernel<<<(BATCH * NL) / 4, 256, 0, stream>>>(lang, f_nrm_l, BATCH * NL);
        dim3 grid(NRB, BATCH);
        distmin_kernel<<<grid, 256, 0, stream>>>(video, lang, f_nrm_v, f_nrm_l, f_rowmin, f_colpart);
        reduce_kernel<<<BATCH, 256, 0, stream>>>(f_rowmin, f_colpart, out);
    }
}

// Round 3
// 78.324 us; speedup vs baseline: 6.9096x; 1.4511x over previous
//
#include <hip/hip_runtime.h>
#include <math.h>

#define BATCH 64
#define NV 1024
#define NL 512
#define DIM 512
#define TMM 128
#define TNN 128
#define BK 32
#define NKT (DIM / BK)   // 16 K-iterations

typedef __bf16 bf16x8 __attribute__((ext_vector_type(8)));
typedef __bf16 bf16x4 __attribute__((ext_vector_type(4)));
typedef float f32x4 __attribute__((ext_vector_type(4)));

// =====================================================================
// Fused kernel: fp32 load -> (norms, bf16 convert) -> LDS -> MFMA GEMM
// -> distance epilogue -> row/col min partials.
// grid = 2048 (XCD-swizzled to (b, mt, nt)), block = 256 (4 waves 2x2).
// =====================================================================
__global__ __launch_bounds__(256, 2) void fused_distmin_kernel(
    const float* __restrict__ video, const float* __restrict__ lang,
    float* __restrict__ rowpart, float* __restrict__ colpart) {
    // Octet-major LDS: slab o in [0,4) holds k = [o*8, o*8+8) for all rows,
    // 16B per (o,row) entry. Reads (b128) and writes (b64) are bank-even.
    __shared__ __align__(16) ushort AsU[2][4][TMM][8];  // 16 KB
    __shared__ __align__(16) ushort BsU[2][4][TNN][8];  // 16 KB
    __shared__ float anrm[TMM], bnrm[TNN];
    __shared__ float rowred[2][TMM], colred[2][TNN];

    // XCD-aware bijective swizzle: nwg = 2048 = 8 * 256.
    const int wg = ((blockIdx.x & 7) << 8) | (blockIdx.x >> 3);
    const int b = wg >> 5;          // 64 batches
    const int r5 = wg & 31;
    const int mt = r5 >> 2;         // 8 video row-blocks
    const int nt = r5 & 3;          // 4 lang col-blocks

    const int tid = threadIdx.x;
    const int lane = tid & 63;
    const int w = tid >> 6;
    const int wrow = w >> 1;        // 0..1
    const int wcol = w & 1;         // 0..1
    const int lr = lane & 15;
    const int g = lane >> 4;        // k-octet for fragment reads

    // staging geometry: thread owns rows {srow+32t}, k-quad skq (4 floats)
    const int srow = tid >> 3;      // 0..31
    const int skq = tid & 7;        // 0..7
    const int o_sl = skq >> 1;      // slab
    const int half = skq & 1;       // 8B half of the 16B entry

    const float* Ath = video + ((size_t)b * NV + (size_t)mt * TMM + srow) * DIM + skq * 4;
    const float* Bth = lang + ((size_t)b * NL + (size_t)nt * TNN + srow) * DIM + skq * 4;

    float nA[4] = {0.f, 0.f, 0.f, 0.f};
    float nB[4] = {0.f, 0.f, 0.f, 0.f};

    f32x4 acc[4][4];
#pragma unroll
    for (int i = 0; i < 4; i++)
#pragma unroll
        for (int j = 0; j < 4; j++) acc[i][j] = (f32x4){0.f, 0.f, 0.f, 0.f};

    float4 va[4], vb[4];

    auto load_chunk = [&](int k0) {
#pragma unroll
        for (int t = 0; t < 4; ++t) {
            va[t] = *(const float4*)(Ath + (size_t)t * 32 * DIM + k0);
            vb[t] = *(const float4*)(Bth + (size_t)t * 32 * DIM + k0);
        }
    };
    auto write_chunk = [&](int buf) {
#pragma unroll
        for (int t = 0; t < 4; ++t) {
            float4 v = va[t];
            nA[t] += v.x * v.x + v.y * v.y + v.z * v.z + v.w * v.w;
            bf16x4 p = {(__bf16)v.x, (__bf16)v.y, (__bf16)v.z, (__bf16)v.w};
            *(bf16x4*)&AsU[buf][o_sl][srow + 32 * t][half * 4] = p;
            float4 u = vb[t];
            nB[t] += u.x * u.x + u.y * u.y + u.z * u.z + u.w * u.w;
            bf16x4 q = {(__bf16)u.x, (__bf16)u.y, (__bf16)u.z, (__bf16)u.w};
            *(bf16x4*)&BsU[buf][o_sl][srow + 32 * t][half * 4] = q;
        }
    };

    // prologue: stage k-tile 0 into buf 0
    load_chunk(0);
    write_chunk(0);
    __syncthreads();

    for (int kt = 0; kt < NKT; ++kt) {
        const int cur = kt & 1;
        const bool more = (kt + 1) < NKT;
        if (more) load_chunk((kt + 1) * BK);   // issue next-tile global loads early

        bf16x8 av[4], bv[4];
#pragma unroll
        for (int fr = 0; fr < 4; ++fr)
            av[fr] = *(const bf16x8*)&AsU[cur][g][wrow * 64 + fr * 16 + lr][0];
#pragma unroll
        for (int fc = 0; fc < 4; ++fc)
            bv[fc] = *(const bf16x8*)&BsU[cur][g][wcol * 64 + fc * 16 + lr][0];
#pragma unroll
        for (int fr = 0; fr < 4; ++fr)
#pragma unroll
            for (int fc = 0; fc < 4; ++fc)
                acc[fr][fc] = __builtin_amdgcn_mfma_f32_16x16x32_bf16(
                    av[fr], bv[fc], acc[fr][fc], 0, 0, 0);

        if (more) write_chunk(cur ^ 1);        // cvt + norm-fma + ds_write after MFMA
        __syncthreads();
    }

    // ---- norms: reduce partials across the 8 threads sharing each row ----
#pragma unroll
    for (int t = 0; t < 4; ++t) {
#pragma unroll
        for (int s = 1; s < 8; s <<= 1) {
            nA[t] += __shfl_xor(nA[t], s);
            nB[t] += __shfl_xor(nB[t], s);
        }
    }
    if ((tid & 7) == 0) {
#pragma unroll
        for (int t = 0; t < 4; ++t) {
            anrm[srow + 32 * t] = nA[t];
            bnrm[srow + 32 * t] = nB[t];
        }
    }
    __syncthreads();

    // ---- epilogue: d = |v|^2 - 2 dot + |l|^2, row/col mins (proven R2 code) ----
    const int rgrp = (lane >> 4) * 4;
    float anorm[4][4];
#pragma unroll
    for (int fr = 0; fr < 4; ++fr)
#pragma unroll
        for (int r = 0; r < 4; ++r)
            anorm[fr][r] = anrm[wrow * 64 + fr * 16 + rgrp + r];
    float bnorm[4];
#pragma unroll
    for (int fc = 0; fc < 4; ++fc)
        bnorm[fc] = bnrm[wcol * 64 + fc * 16 + lr];

    float rmin[4][4];
    float cmin[4];
#pragma unroll
    for (int fr = 0; fr < 4; ++fr)
#pragma unroll
        for (int r = 0; r < 4; ++r) rmin[fr][r] = INFINITY;
#pragma unroll
    for (int fc = 0; fc < 4; ++fc) cmin[fc] = INFINITY;

#pragma unroll
    for (int fr = 0; fr < 4; ++fr)
#pragma unroll
        for (int fc = 0; fc < 4; ++fc)
#pragma unroll
            for (int r = 0; r < 4; ++r) {
                float d = anorm[fr][r] - 2.0f * acc[fr][fc][r] + bnorm[fc];
                rmin[fr][r] = fminf(rmin[fr][r], d);
                cmin[fc] = fminf(cmin[fc], d);
            }

#pragma unroll
    for (int fr = 0; fr < 4; ++fr)
#pragma unroll
        for (int r = 0; r < 4; ++r) {
#pragma unroll
            for (int off = 1; off < 16; off <<= 1)
                rmin[fr][r] = fminf(rmin[fr][r], __shfl_xor(rmin[fr][r], off));
        }
#pragma unroll
    for (int fc = 0; fc < 4; ++fc) {
#pragma unroll
        for (int off = 16; off < 64; off <<= 1)
            cmin[fc] = fminf(cmin[fc], __shfl_xor(cmin[fc], off));
    }

    if ((lane & 15) == 0) {
#pragma unroll
        for (int fr = 0; fr < 4; ++fr)
#pragma unroll
            for (int r = 0; r < 4; ++r)
                rowred[wcol][wrow * 64 + fr * 16 + rgrp + r] = rmin[fr][r];
    }
    if (lane < 16) {
#pragma unroll
        for (int fc = 0; fc < 4; ++fc)
            colred[wrow][wcol * 64 + fc * 16 + lane] = cmin[fc];
    }
    __syncthreads();
    if (tid < TMM) {
        rowpart[((size_t)(b * 4 + nt)) * NV + mt * TMM + tid] =
            fminf(rowred[0][tid], rowred[1][tid]);
    } else {
        int c2 = tid - TMM;
        colpart[((size_t)(b * 8 + mt)) * NL + nt * TNN + c2] =
            fminf(colred[0][c2], colred[1][c2]);
    }
}

// ---------------- final reduce ----------------------------------------------
__global__ __launch_bounds__(256) void reduce2_kernel(
    const float* __restrict__ rowpart, const float* __restrict__ colpart,
    float* __restrict__ out) {
    int b = blockIdx.x;
    int tid = threadIdx.x;
    float s = 0.0f;
    for (int r = tid; r < NV; r += 256) {
        float m = INFINITY;
#pragma unroll
        for (int nt = 0; nt < 4; nt++)
            m = fminf(m, rowpart[((size_t)(b * 4 + nt)) * NV + r]);
        s += m * (1.0f / NV);
    }
    for (int c = tid; c < NL; c += 256) {
        float m = INFINITY;
#pragma unroll
        for (int mt = 0; mt < 8; mt++)
            m = fminf(m, colpart[((size_t)(b * 8 + mt)) * NL + c]);
        s += m * (1.0f / NL);
    }
    __shared__ float red[4];
#pragma unroll
    for (int off = 32; off > 0; off >>= 1) s += __shfl_down(s, off);
    if ((tid & 63) == 0) red[tid >> 6] = s;
    __syncthreads();
    if (tid == 0) out[b] = red[0] + red[1] + red[2] + red[3];
}

// ============================================================================
extern "C" void kernel_launch(void* const* d_in, const int* in_sizes, int n_in,
                              void* d_out, int out_size, void* d_ws, size_t ws_size,
                              hipStream_t stream) {
    const float* video = (const float*)d_in[0];  // [64,1024,512] fp32
    const float* lang = (const float*)d_in[1];   // [64,512,512] fp32
    float* out = (float*)d_out;                  // [64]

    float* rowpart = (float*)d_ws;                      // 64*4*1024 floats (1 MB)
    float* colpart = rowpart + (size_t)BATCH * 4 * NV;  // 64*8*512 floats (1 MB)

    fused_distmin_kernel<<<dim3(2048), 256, 0, stream>>>(video, lang, rowpart, colpart);
    reduce2_kernel<<<BATCH, 256, 0, stream>>>(rowpart, colpart, out);
}